// Round 1
// baseline (507.407 us; speedup 1.0000x reference)
//
#include <hip/hip_runtime.h>

#define BATCH 8192
#define NUM_SV 8192
#define DIM 256
#define GAMMA 0.1f

#define BM 64
#define BS 128
#define BK 32
#define SCHUNK 4
#define S_PER (NUM_SV / SCHUNK)   // 2048
#define LDA (BM + 4)              // 68 floats: keeps float4 reads 16B-aligned, spreads banks
#define LDB (BS + 4)              // 132

// ---------------- row squared-norms: xsq[b], svsq[s] ----------------
__global__ __launch_bounds__(256)
void svm_rowsq(const float* __restrict__ x, const float* __restrict__ sv,
               float* __restrict__ xsq, float* __restrict__ svsq) {
  int row  = blockIdx.x * 4 + (threadIdx.x >> 6);
  int lane = threadIdx.x & 63;
  const float* src;
  float* dst;
  if (row < BATCH) { src = x + (size_t)row * DIM; dst = xsq + row; }
  else             { src = sv + (size_t)(row - BATCH) * DIM; dst = svsq + (row - BATCH); }
  float4 v = *(const float4*)(src + lane * 4);   // 256 = 64 lanes * 4
  float s = v.x*v.x + v.y*v.y + v.z*v.z + v.w*v.w;
  #pragma unroll
  for (int off = 32; off > 0; off >>= 1) s += __shfl_down(s, off, 64);
  if (lane == 0) *dst = s;
}

// ---------------- main fused kernel ----------------
// Block: 256 threads = 16(tm) x 16(ts). Tile: BM=64 b-rows x BS=128 s-cols.
// Each thread: 4 b x 8 s accumulators. K staged in LDS chunks of BK=32,
// k-major layout so fragment reads are float4 (ds_read_b128).
__global__ __launch_bounds__(256, 2)
void svm_main(const float* __restrict__ x, const float* __restrict__ sv,
              const float* __restrict__ dual, const float* __restrict__ xsq,
              const float* __restrict__ svsq, float* __restrict__ partial) {
  __shared__ float xs[BK][LDA];
  __shared__ float ss[BK][LDB];
  __shared__ float red[16][BM + 4];

  const int tid   = threadIdx.x;
  const int b0    = blockIdx.x * BM;
  const int chunk = blockIdx.y;
  const int sbeg  = chunk * S_PER;
  const int tm    = tid >> 4;   // 0..15 -> b rows tm*4..tm*4+3
  const int ts    = tid & 15;   // 0..15 -> s cols {ts*4..+3} U {64+ts*4..+3}

  // staging maps (chosen so transposed LDS writes are <=2-way bank aliased)
  const int xr  = (tid >> 1) & 63;                      // x row 0..63
  const int xko = ((tid >> 7) << 4) | ((tid & 1) << 3); // k offset {0,8,16,24}
  const int sr  = tid >> 1;                             // sv row 0..127
  const int sko = (tid & 1) << 4;                       // k offset {0,16}

  float xq[4], contrib[4];
  #pragma unroll
  for (int i = 0; i < 4; ++i) {
    xq[i] = xsq[b0 + tm * 4 + i];
    contrib[i] = 0.f;
  }

  for (int stile = 0; stile < S_PER / BS; ++stile) {
    const int s0 = sbeg + stile * BS;
    float acc[4][8];
    #pragma unroll
    for (int i = 0; i < 4; ++i)
      #pragma unroll
      for (int j = 0; j < 8; ++j) acc[i][j] = 0.f;

    for (int kc = 0; kc < DIM / BK; ++kc) {
      const int k0 = kc * BK;
      // issue global loads early (overlap with previous compute)
      const float* gx = x + (size_t)(b0 + xr) * DIM + k0 + xko;
      float4 a0 = *(const float4*)gx;
      float4 a1 = *(const float4*)(gx + 4);
      const float* gs = sv + (size_t)(s0 + sr) * DIM + k0 + sko;
      float4 c0 = *(const float4*)gs;
      float4 c1 = *(const float4*)(gs + 4);
      float4 c2 = *(const float4*)(gs + 8);
      float4 c3 = *(const float4*)(gs + 12);

      __syncthreads();  // previous tile's compute done before overwrite
      xs[xko + 0][xr] = a0.x; xs[xko + 1][xr] = a0.y;
      xs[xko + 2][xr] = a0.z; xs[xko + 3][xr] = a0.w;
      xs[xko + 4][xr] = a1.x; xs[xko + 5][xr] = a1.y;
      xs[xko + 6][xr] = a1.z; xs[xko + 7][xr] = a1.w;

      ss[sko +  0][sr] = c0.x; ss[sko +  1][sr] = c0.y;
      ss[sko +  2][sr] = c0.z; ss[sko +  3][sr] = c0.w;
      ss[sko +  4][sr] = c1.x; ss[sko +  5][sr] = c1.y;
      ss[sko +  6][sr] = c1.z; ss[sko +  7][sr] = c1.w;
      ss[sko +  8][sr] = c2.x; ss[sko +  9][sr] = c2.y;
      ss[sko + 10][sr] = c2.z; ss[sko + 11][sr] = c2.w;
      ss[sko + 12][sr] = c3.x; ss[sko + 13][sr] = c3.y;
      ss[sko + 14][sr] = c3.z; ss[sko + 15][sr] = c3.w;
      __syncthreads();

      #pragma unroll 4
      for (int k = 0; k < BK; ++k) {
        float4 xa = *(const float4*)&xs[k][tm * 4];
        float4 sa = *(const float4*)&ss[k][ts * 4];
        float4 sb = *(const float4*)&ss[k][64 + ts * 4];
        acc[0][0] += xa.x * sa.x; acc[0][1] += xa.x * sa.y;
        acc[0][2] += xa.x * sa.z; acc[0][3] += xa.x * sa.w;
        acc[0][4] += xa.x * sb.x; acc[0][5] += xa.x * sb.y;
        acc[0][6] += xa.x * sb.z; acc[0][7] += xa.x * sb.w;
        acc[1][0] += xa.y * sa.x; acc[1][1] += xa.y * sa.y;
        acc[1][2] += xa.y * sa.z; acc[1][3] += xa.y * sa.w;
        acc[1][4] += xa.y * sb.x; acc[1][5] += xa.y * sb.y;
        acc[1][6] += xa.y * sb.z; acc[1][7] += xa.y * sb.w;
        acc[2][0] += xa.z * sa.x; acc[2][1] += xa.z * sa.y;
        acc[2][2] += xa.z * sa.z; acc[2][3] += xa.z * sa.w;
        acc[2][4] += xa.z * sb.x; acc[2][5] += xa.z * sb.y;
        acc[2][6] += xa.z * sb.z; acc[2][7] += xa.z * sb.w;
        acc[3][0] += xa.w * sa.x; acc[3][1] += xa.w * sa.y;
        acc[3][2] += xa.w * sa.z; acc[3][3] += xa.w * sa.w;
        acc[3][4] += xa.w * sb.x; acc[3][5] += xa.w * sb.y;
        acc[3][6] += xa.w * sb.z; acc[3][7] += xa.w * sb.w;
      }
      __syncthreads();
    }

    // fused epilogue for this s-tile
    #pragma unroll
    for (int j = 0; j < 8; ++j) {
      const int sl = (j < 4) ? (ts * 4 + j) : (64 + ts * 4 + (j - 4));
      const int s  = s0 + sl;
      const float svq = svsq[s];
      const float dc  = dual[s];
      #pragma unroll
      for (int i = 0; i < 4; ++i) {
        float d = fmaxf(xq[i] + svq - 2.0f * acc[i][j], 0.0f);
        contrib[i] += __expf(-GAMMA * d) * dc;
      }
    }
  }

  // reduce contrib across the 16 ts-threads sharing each b row
  __syncthreads();
  #pragma unroll
  for (int i = 0; i < 4; ++i) red[ts][tm * 4 + i] = contrib[i];
  __syncthreads();
  if (tid < BM) {
    float s = 0.f;
    #pragma unroll
    for (int j = 0; j < 16; ++j) s += red[j][tid];
    partial[chunk * BATCH + b0 + tid] = s;
  }
}

// ---------------- final reduction across s-chunks ----------------
__global__ __launch_bounds__(256)
void svm_reduce(const float* __restrict__ partial, float* __restrict__ out) {
  int b = blockIdx.x * 256 + threadIdx.x;
  float s = 0.f;
  #pragma unroll
  for (int c = 0; c < SCHUNK; ++c) s += partial[c * BATCH + b];
  out[b] = s;
}

extern "C" void kernel_launch(void* const* d_in, const int* in_sizes, int n_in,
                              void* d_out, int out_size, void* d_ws, size_t ws_size,
                              hipStream_t stream) {
  const float* x    = (const float*)d_in[0];
  const float* sv   = (const float*)d_in[1];
  const float* dual = (const float*)d_in[2];
  float* out = (float*)d_out;
  float* ws  = (float*)d_ws;

  float* xsq     = ws;                       // BATCH
  float* svsq    = ws + BATCH;               // NUM_SV
  float* partial = ws + BATCH + NUM_SV;      // SCHUNK * BATCH

  svm_rowsq<<<(BATCH + NUM_SV) / 4, 256, 0, stream>>>(x, sv, xsq, svsq);
  svm_main<<<dim3(BATCH / BM, SCHUNK), 256, 0, stream>>>(x, sv, dual, xsq, svsq, partial);
  svm_reduce<<<BATCH / 256, 256, 0, stream>>>(partial, out);
}

// Round 2
// 86.370 us; speedup vs baseline: 5.8748x; 5.8748x over previous
//
#include <hip/hip_runtime.h>

#define BATCH 8192
#define NUM_SV 8192
#define DIM 256
#define GAMMA 0.1f
#define LOG2E 1.4426950408889634f

#define BM 128
#define BS 256
#define BK 32
#define SCHUNK 8
#define S_PER (NUM_SV / SCHUNK)  // 1024
#define NST (S_PER / BS)         // 4 s-tiles per block
#define NKC (DIM / BK)           // 8 k-steps per s-tile

typedef _Float16 f16;
typedef __attribute__((ext_vector_type(8))) _Float16 f16x8;
typedef __attribute__((ext_vector_type(4))) float f32x4;

// LDS tile layout: [row][32 f16], row stride 64B = 4 chunks of 16B (8 f16).
// Chunk-XOR swizzle -> fragment reads (16 lanes, consecutive rows, same chunk)
// land 2-way max on banks (free).
__device__ __forceinline__ int ldsoff(int row, int c) {
  return row * 32 + (((c ^ (row & 3) ^ ((row >> 2) & 3)) & 3) << 3);
}

__device__ __forceinline__ f16x8 cvthi8(float4 u, float4 v) {
  f16x8 h;
  h[0] = (f16)u.x; h[1] = (f16)u.y; h[2] = (f16)u.z; h[3] = (f16)u.w;
  h[4] = (f16)v.x; h[5] = (f16)v.y; h[6] = (f16)v.z; h[7] = (f16)v.w;
  return h;
}
__device__ __forceinline__ f16x8 cvtlo8(float4 u, float4 v, f16x8 h) {
  f16x8 l;
  l[0] = (f16)(u.x - (float)h[0]); l[1] = (f16)(u.y - (float)h[1]);
  l[2] = (f16)(u.z - (float)h[2]); l[3] = (f16)(u.w - (float)h[3]);
  l[4] = (f16)(v.x - (float)h[4]); l[5] = (f16)(v.y - (float)h[5]);
  l[6] = (f16)(v.z - (float)h[6]); l[7] = (f16)(v.w - (float)h[7]);
  return l;
}

// ---------------- scaled row squared-norms: xg = -g*log2e*|x|^2, sg likewise --
__global__ __launch_bounds__(256)
void svm_rowsq(const float* __restrict__ x, const float* __restrict__ sv,
               float* __restrict__ xg, float* __restrict__ sg) {
  int row  = blockIdx.x * 4 + (threadIdx.x >> 6);
  int lane = threadIdx.x & 63;
  const float* src;
  float* dst;
  if (row < BATCH) { src = x + (size_t)row * DIM; dst = xg + row; }
  else             { src = sv + (size_t)(row - BATCH) * DIM; dst = sg + (row - BATCH); }
  float4 v = *(const float4*)(src + lane * 4);
  float s = v.x*v.x + v.y*v.y + v.z*v.z + v.w*v.w;
  #pragma unroll
  for (int off = 32; off > 0; off >>= 1) s += __shfl_down(s, off, 64);
  if (lane == 0) *dst = -(GAMMA * LOG2E) * s;
}

// ---------------- main fused MFMA kernel ----------------
__global__ __launch_bounds__(256, 2)
void svm_main(const float* __restrict__ x, const float* __restrict__ sv,
              const float* __restrict__ dual, const float* __restrict__ xg,
              const float* __restrict__ sg, float* __restrict__ partial) {
  __shared__ f16 xs_hi[BM * BK];   // 8 KB
  __shared__ f16 xs_lo[BM * BK];   // 8 KB
  __shared__ f16 ss_hi[BS * BK];   // 16 KB
  __shared__ float red[2][BM];

  const int tid = threadIdx.x;
  const int w   = tid >> 6;
  const int l   = tid & 63;
  const int lr  = l & 15;   // fragment row/col within 16
  const int lk  = l >> 4;   // k-chunk 0..3
  const int wb  = w >> 1;   // wave b-half (64 rows)
  const int ws  = w & 1;    // wave s-half (128 cols)
  const int b0  = blockIdx.x * BM;
  const int sch = blockIdx.y;

  // staging map: thread handles one row-half (16 fp32 = chunks ac, ac+1)
  const int ar = tid >> 1;        // row 0..127
  const int ac = (tid & 1) * 2;   // first chunk

  const float C2f = 2.0f * GAMMA * LOG2E;

  float xgv[4][4];
  #pragma unroll
  for (int m = 0; m < 4; ++m)
    #pragma unroll
    for (int j = 0; j < 4; ++j)
      xgv[m][j] = xg[b0 + wb * 64 + m * 16 + lk * 4 + j];

  float ctr[4][4];
  #pragma unroll
  for (int m = 0; m < 4; ++m)
    #pragma unroll
    for (int j = 0; j < 4; ++j) ctr[m][j] = 0.f;

  for (int st = 0; st < NST; ++st) {
    const int s0 = sch * S_PER + st * BS;

    f32x4 acc[4][8];
    #pragma unroll
    for (int m = 0; m < 4; ++m)
      #pragma unroll
      for (int n = 0; n < 8; ++n) acc[m][n] = (f32x4){0.f, 0.f, 0.f, 0.f};

    for (int kc = 0; kc < NKC; ++kc) {
      const int k0 = kc * BK;

      // ---- global loads (to regs; overlaps previous MFMA) ----
      const float* ga = x + (size_t)(b0 + ar) * DIM + k0 + ac * 8;
      float4 a0 = *(const float4*)(ga + 0);
      float4 a1 = *(const float4*)(ga + 4);
      float4 a2 = *(const float4*)(ga + 8);
      float4 a3 = *(const float4*)(ga + 12);
      const float* gb0 = sv + (size_t)(s0 + ar) * DIM + k0 + ac * 8;
      float4 p0 = *(const float4*)(gb0 + 0);
      float4 p1 = *(const float4*)(gb0 + 4);
      float4 p2 = *(const float4*)(gb0 + 8);
      float4 p3 = *(const float4*)(gb0 + 12);
      const float* gb1 = sv + (size_t)(s0 + 128 + ar) * DIM + k0 + ac * 8;
      float4 q0 = *(const float4*)(gb1 + 0);
      float4 q1 = *(const float4*)(gb1 + 4);
      float4 q2 = *(const float4*)(gb1 + 8);
      float4 q3 = *(const float4*)(gb1 + 12);

      f16x8 ah0 = cvthi8(a0, a1), ah1 = cvthi8(a2, a3);
      f16x8 al0 = cvtlo8(a0, a1, ah0), al1 = cvtlo8(a2, a3, ah1);
      f16x8 bh0 = cvthi8(p0, p1), bh1 = cvthi8(p2, p3);
      f16x8 ch0 = cvthi8(q0, q1), ch1 = cvthi8(q2, q3);

      __syncthreads();  // previous k-step's fragment reads done
      *(f16x8*)&xs_hi[ldsoff(ar, ac)]           = ah0;
      *(f16x8*)&xs_hi[ldsoff(ar, ac + 1)]       = ah1;
      *(f16x8*)&xs_lo[ldsoff(ar, ac)]           = al0;
      *(f16x8*)&xs_lo[ldsoff(ar, ac + 1)]       = al1;
      *(f16x8*)&ss_hi[ldsoff(ar, ac)]           = bh0;
      *(f16x8*)&ss_hi[ldsoff(ar, ac + 1)]       = bh1;
      *(f16x8*)&ss_hi[ldsoff(128 + ar, ac)]     = ch0;
      *(f16x8*)&ss_hi[ldsoff(128 + ar, ac + 1)] = ch1;
      __syncthreads();

      // ---- fragments + MFMA (2-pass: x_hi*sv_hi + x_lo*sv_hi) ----
      f16x8 bh[8];
      #pragma unroll
      for (int n = 0; n < 8; ++n)
        bh[n] = *(const f16x8*)&ss_hi[ldsoff(ws * 128 + n * 16 + lr, lk)];

      #pragma unroll
      for (int m = 0; m < 4; ++m) {
        const int arow = wb * 64 + m * 16 + lr;
        f16x8 ah = *(const f16x8*)&xs_hi[ldsoff(arow, lk)];
        f16x8 al = *(const f16x8*)&xs_lo[ldsoff(arow, lk)];
        #pragma unroll
        for (int n = 0; n < 8; ++n) {
          acc[m][n] = __builtin_amdgcn_mfma_f32_16x16x32_f16(ah, bh[n], acc[m][n], 0, 0, 0);
          acc[m][n] = __builtin_amdgcn_mfma_f32_16x16x32_f16(al, bh[n], acc[m][n], 0, 0, 0);
        }
      }
    }

    // ---- fused epilogue: arg = xg_r + sg_c + 2*gamma*log2e*cross ----
    #pragma unroll
    for (int n = 0; n < 8; ++n) {
      const int col = s0 + ws * 128 + n * 16 + lr;
      const float sgv = sg[col];
      const float dv  = dual[col];
      #pragma unroll
      for (int m = 0; m < 4; ++m) {
        #pragma unroll
        for (int j = 0; j < 4; ++j) {
          float arg = fmaf(C2f, acc[m][n][j], xgv[m][j] + sgv);
          ctr[m][j] = fmaf(__builtin_amdgcn_exp2f(arg), dv, ctr[m][j]);
        }
      }
    }
  }

  // ---- reduce contrib across the 16 lanes sharing each row set ----
  #pragma unroll
  for (int m = 0; m < 4; ++m)
    #pragma unroll
    for (int j = 0; j < 4; ++j) {
      float v = ctr[m][j];
      v += __shfl_xor(v, 1, 64);
      v += __shfl_xor(v, 2, 64);
      v += __shfl_xor(v, 4, 64);
      v += __shfl_xor(v, 8, 64);
      ctr[m][j] = v;
    }
  if (lr == 0) {
    #pragma unroll
    for (int m = 0; m < 4; ++m)
      #pragma unroll
      for (int j = 0; j < 4; ++j)
        red[ws][wb * 64 + m * 16 + lk * 4 + j] = ctr[m][j];
  }
  __syncthreads();
  if (tid < BM)
    partial[(size_t)sch * BATCH + b0 + tid] = red[0][tid] + red[1][tid];
}

// ---------------- final reduction across s-chunks ----------------
__global__ __launch_bounds__(256)
void svm_reduce(const float* __restrict__ partial, float* __restrict__ out) {
  int b = blockIdx.x * 256 + threadIdx.x;
  float s = 0.f;
  #pragma unroll
  for (int c = 0; c < SCHUNK; ++c) s += partial[(size_t)c * BATCH + b];
  out[b] = s;
}

extern "C" void kernel_launch(void* const* d_in, const int* in_sizes, int n_in,
                              void* d_out, int out_size, void* d_ws, size_t ws_size,
                              hipStream_t stream) {
  const float* x    = (const float*)d_in[0];
  const float* sv   = (const float*)d_in[1];
  const float* dual = (const float*)d_in[2];
  float* out = (float*)d_out;
  float* ws  = (float*)d_ws;

  float* xg      = ws;                        // BATCH
  float* sg      = ws + BATCH;                // NUM_SV
  float* partial = ws + BATCH + NUM_SV;       // SCHUNK * BATCH

  svm_rowsq<<<(BATCH + NUM_SV) / 4, 256, 0, stream>>>(x, sv, xg, sg);
  svm_main<<<dim3(BATCH / BM, SCHUNK), 256, 0, stream>>>(x, sv, dual, xg, sg, partial);
  svm_reduce<<<BATCH / 256, 256, 0, stream>>>(partial, out);
}

// Round 3
// 54.258 us; speedup vs baseline: 9.3517x; 1.5918x over previous
//
#include <hip/hip_runtime.h>

#define BATCH 8192
#define NUM_SV 8192
#define DIM 256
#define GAMMA 0.1f
#define LOG2E 1.4426950408889634f
// sqrt(2*GAMMA*LOG2E) : pre-scale so MFMA acc == log2-exponent contribution
#define ALPHA 0.53715827f

#define BM 256
#define BS 256
#define BK 32
#define SCHUNK 8
#define NST 4                 // s-tiles per block (32 total / SCHUNK)
#define NKC (DIM / BK)        // 8 k-steps per s-tile
#define TILE_F16 8192         // 256 rows * 32 k = 16KB = 8192 f16 (both x and sv tiles)

typedef _Float16 f16;
typedef __attribute__((ext_vector_type(8))) _Float16 f16x8;
typedef __attribute__((ext_vector_type(16))) float f32x16;

__device__ __forceinline__ void gload_lds16(const f16* g, f16* l) {
  __builtin_amdgcn_global_load_lds((const __attribute__((address_space(1))) void*)g,
                                   (__attribute__((address_space(3))) void*)l, 16, 0, 0);
}

// ---------------- pre-pass: scaled fp16 tiled copies + norms + dcp ----------
// Thread handles 8 consecutive f32 of one row. 32 threads/row -> row norm via
// shfl. Output layout per (tile,kc): [c=4][row=256][8 f16] so the main kernel
// stages linearly with global_load_lds and reads fragments conflict-free.
__global__ __launch_bounds__(256)
void svm_prep(const float* __restrict__ x, const float* __restrict__ sv,
              const float* __restrict__ dual,
              f16* __restrict__ x16, f16* __restrict__ sv16,
              float* __restrict__ xg, float* __restrict__ dcp) {
  const int id = blockIdx.x * 256 + threadIdx.x;   // 0 .. 524287
  const bool isx = id < (BATCH * DIM / 8);
  const int lid = isx ? id : id - (BATCH * DIM / 8);
  const int row = lid >> 5;
  const int k0  = (lid & 31) << 3;

  const float* src = (isx ? x : sv) + (size_t)row * DIM + k0;
  float4 u = *(const float4*)(src);
  float4 v = *(const float4*)(src + 4);

  float sq = u.x*u.x + u.y*u.y + u.z*u.z + u.w*u.w
           + v.x*v.x + v.y*v.y + v.z*v.z + v.w*v.w;
  #pragma unroll
  for (int m = 1; m <= 16; m <<= 1) sq += __shfl_xor(sq, m, 32);
  if ((lid & 31) == 0) {
    float g = -(GAMMA * LOG2E) * sq;
    if (isx) xg[row] = g;
    else     dcp[row] = dual[row] * __builtin_amdgcn_exp2f(g);
  }

  f16x8 h;
  h[0] = (f16)(ALPHA * u.x); h[1] = (f16)(ALPHA * u.y);
  h[2] = (f16)(ALPHA * u.z); h[3] = (f16)(ALPHA * u.w);
  h[4] = (f16)(ALPHA * v.x); h[5] = (f16)(ALPHA * v.y);
  h[6] = (f16)(ALPHA * v.z); h[7] = (f16)(ALPHA * v.w);

  const int bt = row >> 8;          // 256-row tile
  const int r  = row & 255;
  const int kc = k0 >> 5;
  const int c  = (k0 >> 3) & 3;
  f16* dst = (isx ? x16 : sv16) + (size_t)(bt * NKC + kc) * TILE_F16 + (c * 256 + r) * 8;
  *(f16x8*)dst = h;
}

// ---------------- main fused MFMA kernel ----------------
// 512 threads = 8 waves (4 wb x 2 wn); wave tile 64 rows x 128 cols as
// 2x4 grid of mfma_f32_32x32x16_f16. Double-buffered LDS, one barrier per
// k-step, global_load_lds prefetch issued right after the barrier.
__global__ __launch_bounds__(512, 2)
void svm_main(const f16* __restrict__ x16, const f16* __restrict__ sv16,
              const float* __restrict__ dcp, float* __restrict__ partial) {
  __shared__ f16 lds[2][2 * TILE_F16];   // 2 x 32KB = 64KB

  const int tid = threadIdx.x;
  const int w   = tid >> 6;
  const int l   = tid & 63;
  const int lr  = l & 31;
  const int lh  = l >> 5;
  const int wb  = w >> 1;        // 0..3 : 64-row strip
  const int wn  = w & 1;         // 0..1 : 128-col strip
  const int sch = blockIdx.x;    // 0..7  (XCD-local s-chunk)
  const int bt  = blockIdx.y;    // 0..31
  const int stile0 = sch * NST;

  f32x16 acc[2][4];
  float ctr[2][16];
  #pragma unroll
  for (int m = 0; m < 2; ++m) {
    #pragma unroll
    for (int n = 0; n < 4; ++n)
      #pragma unroll
      for (int r = 0; r < 16; ++r) acc[m][n][r] = 0.f;
    #pragma unroll
    for (int r = 0; r < 16; ++r) ctr[m][r] = 0.f;
  }

  // stage one k-step (x tile 16KB + sv tile 16KB) into buffer bb
  auto stage = [&](int bb, int stile, int kc) {
    const f16* xb = x16  + (size_t)(bt * NKC + kc) * TILE_F16;
    const f16* sb = sv16 + (size_t)(stile * NKC + kc) * TILE_F16;
    #pragma unroll
    for (int j = 0; j < 4; ++j) {
      const int r = w * 4 + j;                       // 0..31, wave-uniform
      const f16* src = (r < 16) ? (xb + r * 512 + l * 8)
                                : (sb + (r - 16) * 512 + l * 8);
      gload_lds16(src, &lds[bb][r * 512]);
    }
  };

  auto compute = [&](int bb) {
    const f16* buf = lds[bb];
    f16x8 af[2][2], bf[4][2];
    #pragma unroll
    for (int m = 0; m < 2; ++m)
      #pragma unroll
      for (int ks = 0; ks < 2; ++ks)
        af[m][ks] = *(const f16x8*)&buf[((ks * 2 + lh) * 256 + wb * 64 + m * 32 + lr) * 8];
    #pragma unroll
    for (int n = 0; n < 4; ++n)
      #pragma unroll
      for (int ks = 0; ks < 2; ++ks)
        bf[n][ks] = *(const f16x8*)&buf[TILE_F16 + ((ks * 2 + lh) * 256 + wn * 128 + n * 32 + lr) * 8];
    #pragma unroll
    for (int m = 0; m < 2; ++m)
      #pragma unroll
      for (int n = 0; n < 4; ++n) {
        acc[m][n] = __builtin_amdgcn_mfma_f32_32x32x16_f16(af[m][0], bf[n][0], acc[m][n], 0, 0, 0);
        acc[m][n] = __builtin_amdgcn_mfma_f32_32x32x16_f16(af[m][1], bf[n][1], acc[m][n], 0, 0, 0);
      }
  };

  stage(0, stile0, 0);
  int cur = 0;
  for (int t = 0; t < NST * NKC; ++t) {
    __syncthreads();                       // buf[cur] loads drained; prev readers done
    if (t + 1 < NST * NKC)
      stage(cur ^ 1, stile0 + ((t + 1) >> 3), (t + 1) & 7);
    compute(cur);
    if ((t & 7) == 7) {
      const int stile = stile0 + (t >> 3);
      #pragma unroll
      for (int n = 0; n < 4; ++n) {
        const float dv = dcp[stile * 256 + wn * 128 + n * 32 + lr];
        #pragma unroll
        for (int m = 0; m < 2; ++m) {
          #pragma unroll
          for (int r = 0; r < 16; ++r) {
            ctr[m][r] = fmaf(__builtin_amdgcn_exp2f(acc[m][n][r]), dv, ctr[m][r]);
            acc[m][n][r] = 0.f;
          }
        }
      }
    }
    cur ^= 1;
  }

  // reduce ctr across the 32 lanes (lr) sharing each row set
  #pragma unroll
  for (int m = 0; m < 2; ++m)
    #pragma unroll
    for (int r = 0; r < 16; ++r) {
      float v = ctr[m][r];
      v += __shfl_xor(v, 1, 64);
      v += __shfl_xor(v, 2, 64);
      v += __shfl_xor(v, 4, 64);
      v += __shfl_xor(v, 8, 64);
      v += __shfl_xor(v, 16, 64);
      ctr[m][r] = v;
    }

  __syncthreads();                         // LDS buffers free; reuse for red
  float* red = (float*)&lds[0][0];         // [2][256]
  if (lr == 0) {
    #pragma unroll
    for (int m = 0; m < 2; ++m)
      #pragma unroll
      for (int r = 0; r < 16; ++r) {
        const int rl = wb * 64 + m * 32 + (r & 3) + 8 * (r >> 2) + 4 * lh;
        red[wn * 256 + rl] = ctr[m][r];
      }
  }
  __syncthreads();
  if (tid < 256)
    partial[(size_t)sch * BATCH + bt * 256 + tid] = red[tid] + red[256 + tid];
}

// ---------------- final reduction + x-norm factor ----------------
__global__ __launch_bounds__(256)
void svm_reduce(const float* __restrict__ partial, const float* __restrict__ xg,
                float* __restrict__ out) {
  const int b = blockIdx.x * 256 + threadIdx.x;
  float s = 0.f;
  #pragma unroll
  for (int c = 0; c < SCHUNK; ++c) s += partial[(size_t)c * BATCH + b];
  out[b] = __builtin_amdgcn_exp2f(xg[b]) * s;
}

extern "C" void kernel_launch(void* const* d_in, const int* in_sizes, int n_in,
                              void* d_out, int out_size, void* d_ws, size_t ws_size,
                              hipStream_t stream) {
  const float* x    = (const float*)d_in[0];
  const float* sv   = (const float*)d_in[1];
  const float* dual = (const float*)d_in[2];
  float* out = (float*)d_out;

  f16*   x16     = (f16*)d_ws;                       // 4MB
  f16*   sv16    = x16 + (size_t)BATCH * DIM;        // 4MB
  float* xg      = (float*)(sv16 + (size_t)NUM_SV * DIM);
  float* dcp     = xg + BATCH;
  float* partial = dcp + NUM_SV;                     // SCHUNK * BATCH

  svm_prep<<<(BATCH + NUM_SV) * DIM / 8 / 256, 256, 0, stream>>>(x, sv, dual, x16, sv16, xg, dcp);
  svm_main<<<dim3(SCHUNK, BATCH / BM), 512, 0, stream>>>(x16, sv16, dcp, partial);
  svm_reduce<<<BATCH / 256, 256, 0, stream>>>(partial, xg, out);
}